// Round 3
// baseline (1284.527 us; speedup 1.0000x reference)
//
#include <hip/hip_runtime.h>
#include <hip/hip_bf16.h>

#define N_USER 100000
#define N_ITEM 100000
#define NE     300000
#define S      128

typedef __attribute__((ext_vector_type(8))) short short8;
typedef __attribute__((ext_vector_type(4))) float floatx4;

static __device__ __forceinline__ short f2bf(float x) {
  union { float f; unsigned u; } a; a.f = x;
  unsigned r = a.u + 0x7FFFu + ((a.u >> 16) & 1u);   // RNE
  return (short)(r >> 16);
}
static __device__ __forceinline__ short8 ld8f_bf16(const float* p) {
  floatx4 a = *(const floatx4*)p;
  floatx4 b = *(const floatx4*)(p + 4);
  short8 r;
  r[0] = f2bf(a[0]); r[1] = f2bf(a[1]); r[2] = f2bf(a[2]); r[3] = f2bf(a[3]);
  r[4] = f2bf(b[0]); r[5] = f2bf(b[1]); r[6] = f2bf(b[2]); r[7] = f2bf(b[3]);
  return r;
}

// ---------------- kernel 1: last incoming edge per node (segment-max of edge id) ----
__global__ void last_edge_kernel(const int* __restrict__ src, const int* __restrict__ dst,
                                 int* __restrict__ last_u, int* __restrict__ last_v) {
  int i = blockIdx.x * 256 + threadIdx.x;
  if (i < NE) {
    atomicMax(&last_u[src[i]], i);
    atomicMax(&last_v[dst[i]], i);
  }
}

// ---------------- kernel 2: fused gather + GEMM (MFMA bf16) + GRU epilogue ------------
// Logical GEMM: out[row 0..199999][col 0..511] over K=640.
//   col 0..127 r | 128..255 z | 256..383 gin (Wi_n, K<512) | 384..511 ghn (Wh_n, K>=512)
//   K 0..511 = mail [other_mem, own_mem, time_enc, edge_feat] (Wi); K 512..639 = h (Wh)
__global__ __launch_bounds__(256)
void fused_gru_kernel(const float* __restrict__ si, const float* __restrict__ sj,
                      const float* __restrict__ tt, const float* __restrict__ ef,
                      const int* __restrict__ src, const int* __restrict__ dst,
                      const float* __restrict__ Wi, const float* __restrict__ Wh,
                      const float* __restrict__ bi, const float* __restrict__ bh,
                      const float* __restrict__ basis,
                      const int* __restrict__ last_u, const int* __restrict__ last_v,
                      float* __restrict__ out) {
  // A tile: 64 rows x 640 K bf16. Row stride 648 shorts (16B multiple).
  __shared__ __align__(16) short As[64][648];
  // B tile: 384 cols x 32 K bf16, stride padded 32->40.
  __shared__ __align__(16) short Bs[384][40];
  // f32 copy of h for the exact z*h blend. Stride 132 floats.
  __shared__ __align__(16) float Hs[64][132];

  const int tid  = threadIdx.x;
  const int lane = tid & 63;
  const int wave = tid >> 6;           // 0..3
  const int row0 = blockIdx.x * 64;

  // ---------- stage A tile: one row per wave per pass, 8 f32 -> 8 bf16 per lane ------
  const int seg  = lane >> 4;          // 0: other-mem, 1: own-mem, 2: time-enc, 3: edge-feat
  const int soff = (lane & 15) * 8;
  #pragma unroll 1
  for (int rr = 0; rr < 64; rr += 4) {
    int r = rr + wave;
    int g = row0 + r;
    bool isU = g < N_USER;
    int node = isU ? g : g - N_USER;
    const float* hptr = (isU ? si : sj) + (size_t)node * S;
    int l = isU ? last_u[node] : last_v[node];
    short8 v = {0, 0, 0, 0, 0, 0, 0, 0};
    if (l >= 0) {                       // wave-uniform (r is wave-uniform)
      if (seg == 0) {                   // other node's memory
        int o = isU ? dst[l] : src[l];
        const float* optr = (isU ? sj : si) + (size_t)o * S;
        v = ld8f_bf16(optr + soff);
      } else if (seg == 1) {            // own memory as mail content
        v = ld8f_bf16(hptr + soff);
      } else if (seg == 2) {            // time encoding cos(t * basis_freq)
        float tv = tt[l];
        floatx4 b0 = *(const floatx4*)(basis + soff);
        floatx4 b1 = *(const floatx4*)(basis + soff + 4);
        v[0] = f2bf(__cosf(tv * b0[0])); v[1] = f2bf(__cosf(tv * b0[1]));
        v[2] = f2bf(__cosf(tv * b0[2])); v[3] = f2bf(__cosf(tv * b0[3]));
        v[4] = f2bf(__cosf(tv * b1[0])); v[5] = f2bf(__cosf(tv * b1[1]));
        v[6] = f2bf(__cosf(tv * b1[2])); v[7] = f2bf(__cosf(tv * b1[3]));
      } else {                          // edge features
        v = ld8f_bf16(ef + (size_t)l * S + soff);
      }
    }
    *(short8*)&As[r][seg * 128 + soff] = v;
    if (lane < 16) {                    // h block (K 512..639): ALWAYS own memory
      floatx4 h0 = *(const floatx4*)(hptr + soff);
      floatx4 h1 = *(const floatx4*)(hptr + soff + 4);
      short8 hv;
      hv[0] = f2bf(h0[0]); hv[1] = f2bf(h0[1]); hv[2] = f2bf(h0[2]); hv[3] = f2bf(h0[3]);
      hv[4] = f2bf(h1[0]); hv[5] = f2bf(h1[1]); hv[6] = f2bf(h1[2]); hv[7] = f2bf(h1[3]);
      *(short8*)&As[r][512 + soff] = hv;
      *(floatx4*)&Hs[r][soff] = h0;
      *(floatx4*)&Hs[r][soff + 4] = h1;
    }
  }

  // ---------- GEMM: wave owns rows [wave*16, +16) x all 512 gate-cols ----------------
  floatx4 acc[32];
  #pragma unroll
  for (int i = 0; i < 32; ++i) acc[i] = (floatx4){0.f, 0.f, 0.f, 0.f};

  const int m0   = wave * 16;
  const int colb = lane & 15;
  const int kq   = (lane >> 4) * 8;
  const int arow = m0 + colb;

  int rw_[6], pp_[6];
  #pragma unroll
  for (int i = 0; i < 6; ++i) { int ch = i * 256 + tid; rw_[i] = ch >> 2; pp_[i] = (ch & 3) * 8; }

  __syncthreads();                      // A tile staged

  #pragma unroll 1
  for (int ks = 0; ks < 20; ++ks) {
    // load this K-slice of B straight from f32 Wi / Wh, converting to bf16
    short8 g[6];
    if (ks < 16) {
      #pragma unroll
      for (int i = 0; i < 6; ++i)       // cols 0..383 <- Wi rows 0..383, K = ks*32
        g[i] = ld8f_bf16(Wi + (size_t)rw_[i] * 512 + ks * 32 + pp_[i]);
    } else {
      #pragma unroll
      for (int i = 0; i < 6; ++i)       // Bs row rw <- Wh row rw (r,z: 0..255; ghn: 256..383)
        g[i] = ld8f_bf16(Wh + (size_t)rw_[i] * 128 + (ks - 16) * 32 + pp_[i]);
    }
    __syncthreads();                    // previous iteration's B reads complete
    #pragma unroll
    for (int i = 0; i < 6; ++i)
      *(short8*)&Bs[rw_[i]][pp_[i]] = g[i];
    __syncthreads();                    // B slice visible

    short8 af = *(const short8*)&As[arow][ks * 32 + kq];
    if (ks < 16) {                      // r,z,gin -> acc[0..23]
      #pragma unroll
      for (int nt = 0; nt < 24; ++nt) {
        short8 bf = *(const short8*)&Bs[nt * 16 + colb][kq];
        acc[nt] = __builtin_amdgcn_mfma_f32_16x16x32_bf16(af, bf, acc[nt], 0, 0, 0);
      }
    } else {                            // r,z -> acc[0..15]; ghn -> acc[24..31]
      #pragma unroll
      for (int nt = 0; nt < 16; ++nt) {
        short8 bf = *(const short8*)&Bs[nt * 16 + colb][kq];
        acc[nt] = __builtin_amdgcn_mfma_f32_16x16x32_bf16(af, bf, acc[nt], 0, 0, 0);
      }
      #pragma unroll
      for (int nt = 16; nt < 24; ++nt) {
        short8 bf = *(const short8*)&Bs[nt * 16 + colb][kq];
        acc[nt + 8] = __builtin_amdgcn_mfma_f32_16x16x32_bf16(af, bf, acc[nt + 8], 0, 0, 0);
      }
    }
  }

  // ---------- GRU epilogue: C/D layout col=lane&15, row=(lane>>4)*4+reg ---------------
  const int krow = (lane >> 4) * 4;
  #pragma unroll
  for (int j = 0; j < 8; ++j) {
    int c = j * 16 + colb;              // hidden index 0..127
    float br  = bi[c]       + bh[c];
    float bz  = bi[128 + c] + bh[128 + c];
    float bni = bi[256 + c];
    float bnh = bh[256 + c];
    #pragma unroll
    for (int k = 0; k < 4; ++k) {
      int r = m0 + krow + k;
      int g = row0 + r;
      float rpre = acc[j][k]      + br;
      float zpre = acc[8 + j][k]  + bz;
      float gin  = acc[16 + j][k] + bni;
      float ghn  = acc[24 + j][k] + bnh;
      float rg = 1.f / (1.f + __expf(-rpre));
      float zg = 1.f / (1.f + __expf(-zpre));
      float x  = gin + rg * ghn;
      float nn = 1.f - 2.f / (__expf(2.f * x) + 1.f);  // tanh, overflow-safe
      float h  = Hs[r][c];                             // exact f32 h
      out[(size_t)g * S + c] = (1.f - zg) * nn + zg * h;
    }
  }
}

extern "C" void kernel_launch(void* const* d_in, const int* in_sizes, int n_in,
                              void* d_out, int out_size, void* d_ws, size_t ws_size,
                              hipStream_t stream) {
  const float* si    = (const float*)d_in[0];
  const float* sj    = (const float*)d_in[1];
  const float* tt    = (const float*)d_in[2];
  const float* ef    = (const float*)d_in[3];
  const int*   src   = (const int*)d_in[4];
  const int*   dst   = (const int*)d_in[5];
  const float* Wi    = (const float*)d_in[6];
  const float* Wh    = (const float*)d_in[7];
  const float* bi    = (const float*)d_in[8];
  const float* bh    = (const float*)d_in[9];
  const float* basis = (const float*)d_in[10];

  int* last_u = (int*)d_ws;
  int* last_v = last_u + N_USER;

  hipMemsetAsync(last_u, 0xFF, (size_t)(N_USER + N_ITEM) * sizeof(int), stream);
  last_edge_kernel<<<(NE + 255) / 256, 256, 0, stream>>>(src, dst, last_u, last_v);
  fused_gru_kernel<<<(N_USER + N_ITEM) / 64, 256, 0, stream>>>(
      si, sj, tt, ef, src, dst, Wi, Wh, bi, bh, basis, last_u, last_v, (float*)d_out);
}

// Round 4
// 510.922 us; speedup vs baseline: 2.5141x; 2.5141x over previous
//
#include <hip/hip_runtime.h>
#include <hip/hip_bf16.h>

#define N_USER 100000
#define N_ITEM 100000
#define NE     300000
#define S      128

typedef __attribute__((ext_vector_type(8))) short short8;
typedef __attribute__((ext_vector_type(4))) float floatx4;
typedef unsigned long long ull;

static __device__ __forceinline__ short f2bf(float x) {
  union { float f; unsigned u; } a; a.f = x;
  unsigned r = a.u + 0x7FFFu + ((a.u >> 16) & 1u);   // RNE
  return (short)(r >> 16);
}

// ---------------- kernel 1: last incoming edge per node ------------------------------
__global__ void last_edge_kernel(const int* __restrict__ src, const int* __restrict__ dst,
                                 int* __restrict__ last_u, int* __restrict__ last_v) {
  int i = blockIdx.x * 256 + threadIdx.x;
  if (i < NE) {
    atomicMax(&last_u[src[i]], i);
    atomicMax(&last_v[dst[i]], i);
  }
}

// ---------------- kernel 2: pack weights into bf16 MFMA-fragment order ---------------
// Wp[((ks*24 + nt)*64 + lane)*8 + j] = W[col][K],  col = nt*16 + (lane&15),
// K = ks*32 + (lane>>4)*8 + j.  ks<16 -> Wi[col][K] (r,z,gin); ks>=16 -> Wh[col][K-512]
// (cols 0..255 r,z; cols 256..383 = Wh n-rows -> ghn).
__global__ void wpack_kernel(const float* __restrict__ Wi, const float* __restrict__ Wh,
                             short* __restrict__ Wp) {
  int id = blockIdx.x * 256 + threadIdx.x;          // 30720 = 20*24*64
  int ks   = id / 1536;
  int rem  = id - ks * 1536;
  int lane = rem & 63;
  int col  = (rem >> 6) * 16 + (lane & 15);
  int kof  = (lane >> 4) * 8;
  const float* p = (ks < 16) ? (Wi + (size_t)col * 512 + ks * 32 + kof)
                             : (Wh + (size_t)col * 128 + (ks - 16) * 32 + kof);
  floatx4 a = *(const floatx4*)p;
  floatx4 b = *(const floatx4*)(p + 4);
  short8 v;
  v[0] = f2bf(a[0]); v[1] = f2bf(a[1]); v[2] = f2bf(a[2]); v[3] = f2bf(a[3]);
  v[4] = f2bf(b[0]); v[5] = f2bf(b[1]); v[6] = f2bf(b[2]); v[7] = f2bf(b[3]);
  *(short8*)(Wp + (size_t)id * 8) = v;
}

// ---------------- kernel 3: fused gather + barrier-light MFMA GEMM + GRU -------------
// Per block: 64 rows. A staged as MFMA fragments in LDS (two K-phases of 10 ks each).
// B-fragments read per-wave straight from L2-resident Wp (no LDS, no K-loop barriers).
// Wave w owns col-tiles nt = w + 4i, i=0..5 (stride-4 interleave balances ghn tiles).
__global__ __launch_bounds__(256, 2)
void fused_gru_kernel(const float* __restrict__ si, const float* __restrict__ sj,
                      const float* __restrict__ tt, const float* __restrict__ ef,
                      const int* __restrict__ src, const int* __restrict__ dst,
                      const float* __restrict__ bi, const float* __restrict__ bh,
                      const float* __restrict__ basis,
                      const int* __restrict__ last_u, const int* __restrict__ last_v,
                      const short* __restrict__ Wp, const float* __restrict__ zpage,
                      float* __restrict__ out) {
  __shared__ short As[10 * 4 * 64 * 8];      // [ks_rel][rf][lane][8] = 40 KB
  __shared__ ull   Atab[64][4];              // per-row: other / own(mail) / ef / h(own)
  __shared__ float Ttv[64];
  __shared__ float Tsc[64];

  const int tid  = threadIdx.x;
  const int lane = tid & 63;
  const int w    = tid >> 6;
  const int row0 = blockIdx.x * 64;

  // ---------- index phase: resolve all gather pointers (one thread per row) ----------
  if (tid < 64) {
    int g = row0 + tid;
    bool isU = g < N_USER;
    int node = isU ? g : g - N_USER;
    const float* own = (isU ? si : sj) + (size_t)node * S;
    int l = isU ? last_u[node] : last_v[node];
    const float *a0, *a1, *a3; float tv, sc;
    if (l >= 0) {
      int o = isU ? dst[l] : src[l];
      a0 = (isU ? sj : si) + (size_t)o * S;
      a1 = own;
      a3 = ef + (size_t)l * S;
      tv = tt[l]; sc = 1.f;
    } else {
      a0 = zpage; a1 = zpage; a3 = zpage; tv = 0.f; sc = 0.f;
    }
    Atab[tid][0] = (ull)a0; Atab[tid][1] = (ull)a1;
    Atab[tid][2] = (ull)a3; Atab[tid][3] = (ull)own;
    Ttv[tid] = tv; Tsc[tid] = sc;
  }
  __syncthreads();

  floatx4 acc[32];
  #pragma unroll
  for (int i = 0; i < 32; ++i) acc[i] = (floatx4){0.f, 0.f, 0.f, 0.f};

  const int r = tid >> 2;                    // staging row (4 threads/row)

  #pragma unroll 1
  for (int ph = 0; ph < 2; ++ph) {
    if (ph) __syncthreads();                 // phase-0 A reads complete before overwrite

    // ---------- stage A fragments for this phase's 10 K-slices -----------------------
    #pragma unroll 2
    for (int p = 0; p < 10; ++p) {
      int K0  = ph * 320 + p * 32 + (tid & 3) * 8;
      int seg = K0 >> 7;                     // 0 other, 1 own-mail, 2 time, 3 ef, 4 h
      int off = K0 & 127;
      short8 v;
      if (seg == 2) {                        // time encode: cos(t * basis) (*0 if empty)
        float tv = Ttv[r], sc = Tsc[r];
        floatx4 b0 = *(const floatx4*)(basis + off);
        floatx4 b1 = *(const floatx4*)(basis + off + 4);
        v[0] = f2bf(__cosf(tv * b0[0]) * sc); v[1] = f2bf(__cosf(tv * b0[1]) * sc);
        v[2] = f2bf(__cosf(tv * b0[2]) * sc); v[3] = f2bf(__cosf(tv * b0[3]) * sc);
        v[4] = f2bf(__cosf(tv * b1[0]) * sc); v[5] = f2bf(__cosf(tv * b1[1]) * sc);
        v[6] = f2bf(__cosf(tv * b1[2]) * sc); v[7] = f2bf(__cosf(tv * b1[3]) * sc);
      } else {
        int slot = (seg >= 3) ? seg - 1 : seg;
        const float* p0 = (const float*)Atab[r][slot] + off;
        floatx4 a = *(const floatx4*)p0;
        floatx4 b = *(const floatx4*)(p0 + 4);
        v[0] = f2bf(a[0]); v[1] = f2bf(a[1]); v[2] = f2bf(a[2]); v[3] = f2bf(a[3]);
        v[4] = f2bf(b[0]); v[5] = f2bf(b[1]); v[6] = f2bf(b[2]); v[7] = f2bf(b[3]);
      }
      int ksr   = (K0 >> 5) - ph * 10;
      int laneF = (r & 15) + 16 * ((K0 >> 3) & 3);
      *(short8*)&As[(((ksr * 4) + (r >> 4)) * 64 + laneF) * 8] = v;
    }
    __syncthreads();

    // ---------- K loop: no barriers; 1-deep register pipeline on A and B --------------
    short8 bc[6], bn[6], ac[4], an[4];
    #pragma unroll
    for (int i = 0; i < 6; ++i)
      bc[i] = *(const short8*)(Wp + (size_t)(((ph * 10) * 24 + (w + 4 * i)) * 64 + lane) * 8);
    #pragma unroll
    for (int rf = 0; rf < 4; ++rf)
      ac[rf] = *(const short8*)&As[((0 * 4 + rf) * 64 + lane) * 8];

    #pragma unroll 1
    for (int ksr = 0; ksr < 10; ++ksr) {
      if (ksr < 9) {
        #pragma unroll
        for (int i = 0; i < 6; ++i)
          bn[i] = *(const short8*)(Wp + (size_t)(((ph * 10 + ksr + 1) * 24 + (w + 4 * i)) * 64 + lane) * 8);
        #pragma unroll
        for (int rf = 0; rf < 4; ++rf)
          an[rf] = *(const short8*)&As[(((ksr + 1) * 4 + rf) * 64 + lane) * 8];
      }
      #pragma unroll
      for (int i = 0; i < 4; ++i)
        #pragma unroll
        for (int rf = 0; rf < 4; ++rf)
          acc[i * 4 + rf] = __builtin_amdgcn_mfma_f32_16x16x32_bf16(ac[rf], bc[i], acc[i * 4 + rf], 0, 0, 0);
      if (ph == 1 && ksr >= 6) {             // K >= 512: cols 256..383 are ghn
        #pragma unroll
        for (int i = 4; i < 6; ++i)
          #pragma unroll
          for (int rf = 0; rf < 4; ++rf)
            acc[24 + (i - 4) * 4 + rf] = __builtin_amdgcn_mfma_f32_16x16x32_bf16(ac[rf], bc[i], acc[24 + (i - 4) * 4 + rf], 0, 0, 0);
      } else {                               // K < 512: cols 256..383 are gin
        #pragma unroll
        for (int i = 4; i < 6; ++i)
          #pragma unroll
          for (int rf = 0; rf < 4; ++rf)
            acc[i * 4 + rf] = __builtin_amdgcn_mfma_f32_16x16x32_bf16(ac[rf], bc[i], acc[i * 4 + rf], 0, 0, 0);
      }
      #pragma unroll
      for (int i = 0; i < 6; ++i) bc[i] = bn[i];
      #pragma unroll
      for (int rf = 0; rf < 4; ++rf) ac[rf] = an[rf];
    }
  }

  // ---------- GRU epilogue: C/D layout col=lane&15, row=(lane>>4)*4+reg ---------------
  const int colb = lane & 15;
  const int krow = (lane >> 4) * 4;
  #pragma unroll
  for (int h = 0; h < 2; ++h) {
    int c = (w + 4 * h) * 16 + colb;         // hidden index 0..127
    float br  = bi[c]       + bh[c];
    float bz  = bi[128 + c] + bh[128 + c];
    float bni = bi[256 + c];
    float bnh = bh[256 + c];
    #pragma unroll
    for (int rf = 0; rf < 4; ++rf) {
      #pragma unroll
      for (int k = 0; k < 4; ++k) {
        int row = rf * 16 + krow + k;
        int g = row0 + row;
        const float* hp = (g < N_USER) ? (si + (size_t)g * S)
                                       : (sj + (size_t)(g - N_USER) * S);
        float rpre = acc[h * 4 + rf][k]        + br;
        float zpre = acc[(2 + h) * 4 + rf][k]  + bz;
        float gin  = acc[(4 + h) * 4 + rf][k]  + bni;
        float ghn  = acc[24 + h * 4 + rf][k]   + bnh;
        float rg = 1.f / (1.f + __expf(-rpre));
        float zg = 1.f / (1.f + __expf(-zpre));
        float x  = gin + rg * ghn;
        float nn = 1.f - 2.f / (__expf(2.f * x) + 1.f);  // tanh, overflow-safe
        out[(size_t)g * S + c] = (1.f - zg) * nn + zg * hp[c];
      }
    }
  }
}

extern "C" void kernel_launch(void* const* d_in, const int* in_sizes, int n_in,
                              void* d_out, int out_size, void* d_ws, size_t ws_size,
                              hipStream_t stream) {
  const float* si    = (const float*)d_in[0];
  const float* sj    = (const float*)d_in[1];
  const float* tt    = (const float*)d_in[2];
  const float* ef    = (const float*)d_in[3];
  const int*   src   = (const int*)d_in[4];
  const int*   dst   = (const int*)d_in[5];
  const float* Wi    = (const float*)d_in[6];
  const float* Wh    = (const float*)d_in[7];
  const float* bi    = (const float*)d_in[8];
  const float* bh    = (const float*)d_in[9];
  const float* basis = (const float*)d_in[10];

  int*   last_u = (int*)d_ws;                                  // 400 KB
  int*   last_v = last_u + N_USER;                             // 400 KB
  float* zpage  = (float*)((char*)d_ws + 800000);              // 512 B of zeros
  short* Wp     = (short*)((char*)d_ws + (1 << 20));           // 480 KB bf16 fragments

  hipMemsetAsync(last_u, 0xFF, (size_t)(N_USER + N_ITEM) * sizeof(int), stream);
  hipMemsetAsync(zpage, 0, 128 * sizeof(float), stream);
  last_edge_kernel<<<(NE + 255) / 256, 256, 0, stream>>>(src, dst, last_u, last_v);
  wpack_kernel<<<120, 256, 0, stream>>>(Wi, Wh, Wp);
  fused_gru_kernel<<<(N_USER + N_ITEM) / 64, 256, 0, stream>>>(
      si, sj, tt, ef, src, dst, bi, bh, basis, last_u, last_v, Wp, zpage, (float*)d_out);
}